// Round 2
// baseline (354.677 us; speedup 1.0000x reference)
//
#include <hip/hip_runtime.h>
#include <hip/hip_bf16.h>
#include <math.h>

// Problem shapes (fixed by reference setup_inputs)
#define B   256
#define S   196
#define D   1024
#define P   512
#define L   8
#define TOPK 4

#define SSPLIT 7          // S = 7 * 28
#define SCHUNK (S / SSPLIT)

// ---------------------------------------------------------------------------
// Kernel 1a: partial sums over S. grid(B, SSPLIT), block(256).
// Each thread owns 4 contiguous d (one float4), sums 28 rows.
// 1792 blocks -> ~28 waves/CU: enough MLP to reach HBM BW ceiling.
// ---------------------------------------------------------------------------
__global__ __launch_bounds__(256) void mean_partial_kernel(
    const float* __restrict__ x, float* __restrict__ part) {
  const int b = blockIdx.x;
  const int j = blockIdx.y;
  const int t = threadIdx.x;  // 0..255
  const float* xb = x + (size_t)b * S * D + (size_t)j * SCHUNK * D + t * 4;

  float4 acc = make_float4(0.f, 0.f, 0.f, 0.f);
#pragma unroll 4
  for (int s = 0; s < SCHUNK; ++s) {
    float4 v = *(const float4*)(xb + (size_t)s * D);
    acc.x += v.x; acc.y += v.y; acc.z += v.z; acc.w += v.w;
  }
  *(float4*)(part + ((size_t)b * SSPLIT + j) * D + t * 4) = acc;
}

// ---------------------------------------------------------------------------
// Kernel 1b: finalize mean + L2 normalize. grid(B), block(256).
// ---------------------------------------------------------------------------
__global__ __launch_bounds__(256) void mean_norm_finalize_kernel(
    const float* __restrict__ part, float* __restrict__ qn) {
  const int b = blockIdx.x;
  const int t = threadIdx.x;

  float4 acc = make_float4(0.f, 0.f, 0.f, 0.f);
#pragma unroll
  for (int j = 0; j < SSPLIT; ++j) {
    float4 v = *(const float4*)(part + ((size_t)b * SSPLIT + j) * D + t * 4);
    acc.x += v.x; acc.y += v.y; acc.z += v.z; acc.w += v.w;
  }
  const float inv = 1.0f / (float)S;
  acc.x *= inv; acc.y *= inv; acc.z *= inv; acc.w *= inv;

  float ss = acc.x * acc.x + acc.y * acc.y + acc.z * acc.z + acc.w * acc.w;
  for (int off = 32; off > 0; off >>= 1) ss += __shfl_down(ss, off, 64);
  __shared__ float wsum[4];
  __shared__ float snorm;
  const int lane = t & 63, w = t >> 6;
  if (lane == 0) wsum[w] = ss;
  __syncthreads();
  if (t == 0) {
    float tot = wsum[0] + wsum[1] + wsum[2] + wsum[3];
    snorm = rsqrtf(fmaxf(tot, 1e-12f));
  }
  __syncthreads();
  const float r = snorm;
  float4 o = make_float4(acc.x * r, acc.y * r, acc.z * r, acc.w * r);
  *(float4*)(qn + (size_t)b * D + t * 4) = o;
}

// ---------------------------------------------------------------------------
// Kernel 2: key_n = l2_normalize(prompt_key, axis=1). grid(P), block(256).
// ---------------------------------------------------------------------------
__global__ __launch_bounds__(256) void key_norm_kernel(
    const float* __restrict__ pk, float* __restrict__ kn) {
  const int p = blockIdx.x;
  const int t = threadIdx.x;
  float4 v = *(const float4*)(pk + (size_t)p * D + t * 4);
  float ss = v.x * v.x + v.y * v.y + v.z * v.z + v.w * v.w;
  for (int off = 32; off > 0; off >>= 1) ss += __shfl_down(ss, off, 64);
  __shared__ float wsum[4];
  __shared__ float snorm;
  const int lane = t & 63, w = t >> 6;
  if (lane == 0) wsum[w] = ss;
  __syncthreads();
  if (t == 0) {
    float tot = wsum[0] + wsum[1] + wsum[2] + wsum[3];
    snorm = rsqrtf(fmaxf(tot, 1e-12f));
  }
  __syncthreads();
  const float r = snorm;
  float4 o = make_float4(v.x * r, v.y * r, v.z * r, v.w * r);
  *(float4*)(kn + (size_t)p * D + t * 4) = o;
}

// ---------------------------------------------------------------------------
// Kernel 3: sim = q_n @ key_n^T  [B,P], K=D. fp32 vector GEMM, split-K=8,
// 64x64 tile, 4x4 microtile, atomicAdd into zeroed sim buffer.
// grid(B/64, P/64, 8), block(256).
// ---------------------------------------------------------------------------
#define KK 16
__global__ __launch_bounds__(256) void sim_kernel(
    const float* __restrict__ qn, const float* __restrict__ kn,
    float* __restrict__ sim) {
  const int b0 = blockIdx.x * 64;
  const int p0 = blockIdx.y * 64;
  const int k0 = blockIdx.z * (D / 8);  // 128 per split
  const int t = threadIdx.x;
  const int tx = t & 15;   // p micro index
  const int ty = t >> 4;   // b micro index

  __shared__ float As[KK][68];  // [k][b], stride 68 keeps float4 alignment
  __shared__ float Bs[KK][68];  // [k][p]

  float acc[4][4];
#pragma unroll
  for (int i = 0; i < 4; ++i)
#pragma unroll
    for (int j = 0; j < 4; ++j) acc[i][j] = 0.f;

  const int rr = t >> 2;        // 0..63 : row within tile
  const int k4 = (t & 3) * 4;   // 0,4,8,12

  for (int kt = 0; kt < D / 8; kt += KK) {
    float4 a = *(const float4*)(qn + (size_t)(b0 + rr) * D + k0 + kt + k4);
    float4 bb = *(const float4*)(kn + (size_t)(p0 + rr) * D + k0 + kt + k4);
    As[k4 + 0][rr] = a.x; As[k4 + 1][rr] = a.y;
    As[k4 + 2][rr] = a.z; As[k4 + 3][rr] = a.w;
    Bs[k4 + 0][rr] = bb.x; Bs[k4 + 1][rr] = bb.y;
    Bs[k4 + 2][rr] = bb.z; Bs[k4 + 3][rr] = bb.w;
    __syncthreads();
#pragma unroll
    for (int kk = 0; kk < KK; ++kk) {
      float4 av = *(const float4*)&As[kk][ty * 4];
      float4 bv = *(const float4*)&Bs[kk][tx * 4];
      acc[0][0] += av.x * bv.x; acc[0][1] += av.x * bv.y;
      acc[0][2] += av.x * bv.z; acc[0][3] += av.x * bv.w;
      acc[1][0] += av.y * bv.x; acc[1][1] += av.y * bv.y;
      acc[1][2] += av.y * bv.z; acc[1][3] += av.y * bv.w;
      acc[2][0] += av.z * bv.x; acc[2][1] += av.z * bv.y;
      acc[2][2] += av.z * bv.z; acc[2][3] += av.z * bv.w;
      acc[3][0] += av.w * bv.x; acc[3][1] += av.w * bv.y;
      acc[3][2] += av.w * bv.z; acc[3][3] += av.w * bv.w;
    }
    __syncthreads();
  }
#pragma unroll
  for (int i = 0; i < 4; ++i)
#pragma unroll
    for (int j = 0; j < 4; ++j)
      atomicAdd(&sim[(size_t)(b0 + ty * 4 + i) * P + p0 + tx * 4 + j],
                acc[i][j]);
}

// ---------------------------------------------------------------------------
// Kernel 4: 4 rounds of Gumbel argmax with -1000 exclusion.
// grid(B), block(256). First-index tie-break (matches jnp.argmax).
// ---------------------------------------------------------------------------
__global__ __launch_bounds__(256) void select_kernel(
    const float* __restrict__ sim, const float* __restrict__ gu,
    int* __restrict__ idx) {
  const int b = blockIdx.x;
  const int t = threadIdx.x;
  __shared__ float cur[P];
  cur[t] = sim[(size_t)b * P + t];
  cur[t + 256] = sim[(size_t)b * P + t + 256];
  __syncthreads();

  __shared__ float wval[4];
  __shared__ int widx[4];

  for (int i = 0; i < TOPK; ++i) {
    const float* gui = gu + ((size_t)i * B + b) * P;
    float u0 = gui[t];
    float u1 = gui[t + 256];
    float g0 = -logf(-logf(u0 + 1e-10f) + 1e-10f);
    float g1 = -logf(-logf(u1 + 1e-10f) + 1e-10f);
    float v0 = cur[t] + g0;
    float v1 = cur[t + 256] + g1;
    float bv = v0; int bi = t;
    if (v1 > bv) { bv = v1; bi = t + 256; }
    for (int off = 32; off > 0; off >>= 1) {
      float ov = __shfl_down(bv, off, 64);
      int oi = __shfl_down(bi, off, 64);
      if (ov > bv || (ov == bv && oi < bi)) { bv = ov; bi = oi; }
    }
    const int lane = t & 63, w = t >> 6;
    if (lane == 0) { wval[w] = bv; widx[w] = bi; }
    __syncthreads();
    if (t == 0) {
      float bestv = wval[0]; int besti = widx[0];
      for (int k = 1; k < 4; ++k)
        if (wval[k] > bestv || (wval[k] == bestv && widx[k] < besti)) {
          bestv = wval[k]; besti = widx[k];
        }
      idx[i * B + b] = besti;
      cur[besti] -= 1000.0f;  // hard mask-out for next round
    }
    __syncthreads();
  }
}

// ---------------------------------------------------------------------------
// Kernel 5: gather out[b, i*L + l, :] = prompt[idx[i][b], l, :]
// grid(B, TOPK), block(256), float4 copy.
// ---------------------------------------------------------------------------
__global__ __launch_bounds__(256) void gather_kernel(
    const int* __restrict__ idx, const float* __restrict__ prompt,
    float* __restrict__ out) {
  const int b = blockIdx.x;
  const int i = blockIdx.y;
  const int t = threadIdx.x;
  const int p = idx[i * B + b];
  const float4* src = (const float4*)(prompt + (size_t)p * L * D);
  float4* dst = (float4*)(out + ((size_t)b * (TOPK * L) + i * L) * D);
#pragma unroll
  for (int l = 0; l < L; ++l) {
    dst[l * (D / 4) + t] = src[l * (D / 4) + t];
  }
}

// ---------------------------------------------------------------------------
extern "C" void kernel_launch(void* const* d_in, const int* in_sizes, int n_in,
                              void* d_out, int out_size, void* d_ws,
                              size_t ws_size, hipStream_t stream) {
  const float* x_embed    = (const float*)d_in[0];  // [B,S,D]
  const float* prompt     = (const float*)d_in[1];  // [P,L,D]
  const float* prompt_key = (const float*)d_in[2];  // [P,D]
  const float* gumbel_u   = (const float*)d_in[3];  // [TOPK,B,P]
  float* out = (float*)d_out;                       // [B,TOPK*L,D]

  // ws layout (~11 MB): sim | q_n | key_n | idx | part
  float* sim  = (float*)d_ws;                 // B*P      = 131072 f
  float* qn   = sim + (size_t)B * P;          // B*D      = 262144 f
  float* kn   = qn + (size_t)B * D;           // P*D      = 524288 f
  int*   idx  = (int*)(kn + (size_t)P * D);   // TOPK*B   = 1024 i
  float* part = (float*)(idx + TOPK * B);     // B*SSPLIT*D = 1835008 f

  hipMemsetAsync(sim, 0, (size_t)B * P * sizeof(float), stream);

  mean_partial_kernel<<<dim3(B, SSPLIT), 256, 0, stream>>>(x_embed, part);
  mean_norm_finalize_kernel<<<B, 256, 0, stream>>>(part, qn);
  key_norm_kernel<<<P, 256, 0, stream>>>(prompt_key, kn);
  sim_kernel<<<dim3(B / 64, P / 64, 8), 256, 0, stream>>>(qn, kn, sim);
  select_kernel<<<B, 256, 0, stream>>>(sim, gumbel_u, idx);
  gather_kernel<<<dim3(B, TOPK), 256, 0, stream>>>(idx, prompt, out);
}

// Round 3
// 329.393 us; speedup vs baseline: 1.0768x; 1.0768x over previous
//
#include <hip/hip_runtime.h>
#include <hip/hip_bf16.h>
#include <math.h>

// Problem shapes (fixed by reference setup_inputs)
#define B   256
#define S   196
#define D   1024
#define P   512
#define L   8
#define TOPK 4

#define SSPLIT 7          // S = 7 * 28
#define SCHUNK (S / SSPLIT)
#define KSPLIT 8          // split-K for sim

// ---------------------------------------------------------------------------
// Kernel 1: partial sums over S. grid(B, SSPLIT), block(256).
// 1792 blocks -> ~7 blocks/CU; float4 streaming, HBM-BW-bound (205 MB read).
// ---------------------------------------------------------------------------
__global__ __launch_bounds__(256) void mean_partial_kernel(
    const float* __restrict__ x, float* __restrict__ part) {
  const int b = blockIdx.x;
  const int j = blockIdx.y;
  const int t = threadIdx.x;  // 0..255
  const float* xb = x + (size_t)b * S * D + (size_t)j * SCHUNK * D + t * 4;

  float4 acc = make_float4(0.f, 0.f, 0.f, 0.f);
#pragma unroll 4
  for (int s = 0; s < SCHUNK; ++s) {
    float4 v = *(const float4*)(xb + (size_t)s * D);
    acc.x += v.x; acc.y += v.y; acc.z += v.z; acc.w += v.w;
  }
  *(float4*)(part + ((size_t)b * SSPLIT + j) * D + t * 4) = acc;
}

// ---------------------------------------------------------------------------
// Kernel 2 (merged): blocks [0,B) finalize mean+L2norm -> qn;
// blocks [B, B+P) L2-normalize prompt_key -> kn. block(256).
// ---------------------------------------------------------------------------
__global__ __launch_bounds__(256) void norm_kernel(
    const float* __restrict__ part, const float* __restrict__ pk,
    float* __restrict__ qn, float* __restrict__ kn) {
  const int t = threadIdx.x;
  float4 acc;
  float* dst;

  if (blockIdx.x < B) {
    const int b = blockIdx.x;
    acc = make_float4(0.f, 0.f, 0.f, 0.f);
#pragma unroll
    for (int j = 0; j < SSPLIT; ++j) {
      float4 v = *(const float4*)(part + ((size_t)b * SSPLIT + j) * D + t * 4);
      acc.x += v.x; acc.y += v.y; acc.z += v.z; acc.w += v.w;
    }
    const float inv = 1.0f / (float)S;
    acc.x *= inv; acc.y *= inv; acc.z *= inv; acc.w *= inv;
    dst = qn + (size_t)b * D + t * 4;
  } else {
    const int p = blockIdx.x - B;
    acc = *(const float4*)(pk + (size_t)p * D + t * 4);
    dst = kn + (size_t)p * D + t * 4;
  }

  float ss = acc.x * acc.x + acc.y * acc.y + acc.z * acc.z + acc.w * acc.w;
  for (int off = 32; off > 0; off >>= 1) ss += __shfl_down(ss, off, 64);
  __shared__ float wsum[4];
  __shared__ float snorm;
  const int lane = t & 63, w = t >> 6;
  if (lane == 0) wsum[w] = ss;
  __syncthreads();
  if (t == 0) {
    float tot = wsum[0] + wsum[1] + wsum[2] + wsum[3];
    snorm = rsqrtf(fmaxf(tot, 1e-12f));
  }
  __syncthreads();
  const float r = snorm;
  *(float4*)dst = make_float4(acc.x * r, acc.y * r, acc.z * r, acc.w * r);
}

// ---------------------------------------------------------------------------
// Kernel 3: sim partials = q_n @ key_n^T, split-K=8, NO atomics:
// simp[z][b][p]. grid(B/64, P/64, KSPLIT), block(256), 64x64 tile, 4x4 micro.
// ---------------------------------------------------------------------------
#define KK 16
__global__ __launch_bounds__(256) void sim_kernel(
    const float* __restrict__ qn, const float* __restrict__ kn,
    float* __restrict__ simp) {
  const int b0 = blockIdx.x * 64;
  const int p0 = blockIdx.y * 64;
  const int z  = blockIdx.z;
  const int k0 = z * (D / KSPLIT);  // 128 per split
  const int t = threadIdx.x;
  const int tx = t & 15;   // p micro index
  const int ty = t >> 4;   // b micro index

  __shared__ float As[KK][68];  // [k][b]
  __shared__ float Bs[KK][68];  // [k][p]

  float acc[4][4];
#pragma unroll
  for (int i = 0; i < 4; ++i)
#pragma unroll
    for (int j = 0; j < 4; ++j) acc[i][j] = 0.f;

  const int rr = t >> 2;        // 0..63 : row within tile
  const int k4 = (t & 3) * 4;   // 0,4,8,12

  for (int kt = 0; kt < D / KSPLIT; kt += KK) {
    float4 a = *(const float4*)(qn + (size_t)(b0 + rr) * D + k0 + kt + k4);
    float4 bb = *(const float4*)(kn + (size_t)(p0 + rr) * D + k0 + kt + k4);
    As[k4 + 0][rr] = a.x; As[k4 + 1][rr] = a.y;
    As[k4 + 2][rr] = a.z; As[k4 + 3][rr] = a.w;
    Bs[k4 + 0][rr] = bb.x; Bs[k4 + 1][rr] = bb.y;
    Bs[k4 + 2][rr] = bb.z; Bs[k4 + 3][rr] = bb.w;
    __syncthreads();
#pragma unroll
    for (int kk = 0; kk < KK; ++kk) {
      float4 av = *(const float4*)&As[kk][ty * 4];
      float4 bv = *(const float4*)&Bs[kk][tx * 4];
      acc[0][0] += av.x * bv.x; acc[0][1] += av.x * bv.y;
      acc[0][2] += av.x * bv.z; acc[0][3] += av.x * bv.w;
      acc[1][0] += av.y * bv.x; acc[1][1] += av.y * bv.y;
      acc[1][2] += av.y * bv.z; acc[1][3] += av.y * bv.w;
      acc[2][0] += av.z * bv.x; acc[2][1] += av.z * bv.y;
      acc[2][2] += av.z * bv.z; acc[2][3] += av.z * bv.w;
      acc[3][0] += av.w * bv.x; acc[3][1] += av.w * bv.y;
      acc[3][2] += av.w * bv.z; acc[3][3] += av.w * bv.w;
    }
    __syncthreads();
  }
#pragma unroll
  for (int i = 0; i < 4; ++i)
#pragma unroll
    for (int j = 0; j < 4; ++j)
      simp[((size_t)z * B + b0 + ty * 4 + i) * P + p0 + tx * 4 + j] =
          acc[i][j];
}

// ---------------------------------------------------------------------------
// Kernel 4 (fused select+gather): reduce split-K partials, 4 rounds of
// Gumbel argmax with -1000 exclusion, then gather the 4 selected prompt
// rows into out. grid(B), block(256).
// ---------------------------------------------------------------------------
__global__ __launch_bounds__(256) void select_gather_kernel(
    const float* __restrict__ simp, const float* __restrict__ gu,
    const float* __restrict__ prompt, float* __restrict__ out) {
  const int b = blockIdx.x;
  const int t = threadIdx.x;
  __shared__ float cur[P];

  float c0 = 0.f, c1 = 0.f;
#pragma unroll
  for (int z = 0; z < KSPLIT; ++z) {
    c0 += simp[((size_t)z * B + b) * P + t];
    c1 += simp[((size_t)z * B + b) * P + t + 256];
  }
  cur[t] = c0;
  cur[t + 256] = c1;
  __syncthreads();

  __shared__ float wval[4];
  __shared__ int widx[4];
  __shared__ int sidx[TOPK];

  for (int i = 0; i < TOPK; ++i) {
    const float* gui = gu + ((size_t)i * B + b) * P;
    float u0 = gui[t];
    float u1 = gui[t + 256];
    float g0 = -logf(-logf(u0 + 1e-10f) + 1e-10f);
    float g1 = -logf(-logf(u1 + 1e-10f) + 1e-10f);
    float v0 = cur[t] + g0;
    float v1 = cur[t + 256] + g1;
    float bv = v0; int bi = t;
    if (v1 > bv) { bv = v1; bi = t + 256; }
    for (int off = 32; off > 0; off >>= 1) {
      float ov = __shfl_down(bv, off, 64);
      int oi = __shfl_down(bi, off, 64);
      if (ov > bv || (ov == bv && oi < bi)) { bv = ov; bi = oi; }
    }
    const int lane = t & 63, w = t >> 6;
    if (lane == 0) { wval[w] = bv; widx[w] = bi; }
    __syncthreads();
    if (t == 0) {
      float bestv = wval[0]; int besti = widx[0];
      for (int k = 1; k < 4; ++k)
        if (wval[k] > bestv || (wval[k] == bestv && widx[k] < besti)) {
          bestv = wval[k]; besti = widx[k];
        }
      sidx[i] = besti;
      cur[besti] -= 1000.0f;  // hard mask-out for next round
    }
    __syncthreads();
  }

  // gather: out[b, i*L + l, :] = prompt[sidx[i], l, :]
#pragma unroll
  for (int i = 0; i < TOPK; ++i) {
    const int p = sidx[i];
    const float4* src = (const float4*)(prompt + (size_t)p * L * D);
    float4* dst = (float4*)(out + ((size_t)b * (TOPK * L) + i * L) * D);
#pragma unroll
    for (int l = 0; l < L; ++l) {
      dst[l * (D / 4) + t] = src[l * (D / 4) + t];
    }
  }
}

// ---------------------------------------------------------------------------
extern "C" void kernel_launch(void* const* d_in, const int* in_sizes, int n_in,
                              void* d_out, int out_size, void* d_ws,
                              size_t ws_size, hipStream_t stream) {
  const float* x_embed    = (const float*)d_in[0];  // [B,S,D]
  const float* prompt     = (const float*)d_in[1];  // [P,L,D]
  const float* prompt_key = (const float*)d_in[2];  // [P,D]
  const float* gumbel_u   = (const float*)d_in[3];  // [TOPK,B,P]
  float* out = (float*)d_out;                       // [B,TOPK*L,D]

  // ws layout (~14.3 MB): simp | q_n | key_n | part
  float* simp = (float*)d_ws;                      // KSPLIT*B*P = 1048576 f
  float* qn   = simp + (size_t)KSPLIT * B * P;     // B*D        =  262144 f
  float* kn   = qn + (size_t)B * D;                // P*D        =  524288 f
  float* part = kn + (size_t)P * D;                // B*SSPLIT*D = 1835008 f

  mean_partial_kernel<<<dim3(B, SSPLIT), 256, 0, stream>>>(x_embed, part);
  norm_kernel<<<B + P, 256, 0, stream>>>(part, prompt_key, qn, kn);
  sim_kernel<<<dim3(B / 64, P / 64, KSPLIT), 256, 0, stream>>>(qn, kn, simp);
  select_gather_kernel<<<B, 256, 0, stream>>>(simp, gumbel_u, prompt, out);
}